// Round 6
// baseline (82.871 us; speedup 1.0000x reference)
//
#include <hip/hip_runtime.h>
#include <stdint.h>
#include <math.h>

// E8P codebook argmax, 2 rows/wave. Per (absi,p): t_j = |w_j|*(x_j+0.25p)
// (p=1 in 4x-scaled domain via fma(t0,4,w)); best/2nd-best even-parity sign
// flips are closed-form via a payload-packed f64 (min,2nd-min) tournament
// ((2|w|,j,shufbit) in low 16 mantissa bits, 2^-36 rel perturbation).
// score = 2*fl32(exact-ish f64 dot) - gn, gn reconstructed exactly in f32.
// ties -> lower c.  Output float32-flat: [vals|idxs|packed-as-int32-wrap].

__device__ __forceinline__ void cmp_keep(float& bs, int& bc, float s, int c) {
    if (s > bs || (s == bs && c < bc)) { bs = s; bc = c; }
}

__device__ __forceinline__ double pay_abs(double t, uint32_t pk16) {
    long long ll = __double_as_longlong(t) & 0x7FFFFFFFFFFF0000ll;
    return __longlong_as_double(ll | (long long)pk16);
}

struct TournOut { double a1c, a2c; uint32_t q1, q2; };

__device__ __forceinline__ TournOut tourn8(const double kk[8]) {
    double m01 = fmin(kk[0], kk[1]), x01 = fmax(kk[0], kk[1]);
    double m23 = fmin(kk[2], kk[3]), x23 = fmax(kk[2], kk[3]);
    double m45 = fmin(kk[4], kk[5]), x45 = fmax(kk[4], kk[5]);
    double m67 = fmin(kk[6], kk[7]), x67 = fmax(kk[6], kk[7]);
    double mA = fmin(m01, m23), sA = fmin(fmax(m01, m23), fmin(x01, x23));
    double mB = fmin(m45, m67), sB = fmin(fmax(m45, m67), fmin(x45, x67));
    double m1 = fmin(mA, mB),   m2 = fmin(fmax(mA, mB), fmin(sA, sB));
    long long b1 = __double_as_longlong(m1);
    long long b2 = __double_as_longlong(m2);
    TournOut o;
    o.a1c = __longlong_as_double(b1 & ~0xFFFFll);
    o.a2c = __longlong_as_double(b2 & ~0xFFFFll);
    o.q1 = (uint32_t)b1 & 0xFFFFu;
    o.q2 = (uint32_t)b2 & 0xFFFFu;
    return o;
}

__global__ __launch_bounds__(256, 4) void e8p_fused2(
    const float* __restrict__ X,
    const float* __restrict__ grid,
    const float* __restrict__ grid_norm,
    float* __restrict__ out)
{
    __shared__ float2   sWp[4][256];    // |w| element-pairs, transposed (2-way free)
    __shared__ uint32_t sPK[4][256];    // payload u16 pairs, transposed (conflict-free)
    __shared__ uint32_t sMeta[256];     // wsgnshuf | (wpar<<8)
    __shared__ float    sSN[256];
    __shared__ int      sC[4][2];

    const int tid = threadIdx.x;
    const int shuf[8] = {0, 4, 1, 5, 2, 6, 3, 7};

    {   // ---- stage per-absi tables (tid == absi) ----
        const float4* g4 = reinterpret_cast<const float4*>(grid + (size_t)tid * 2048);
        float4 lo = g4[0], hi = g4[1];
        float w[8] = {lo.x, lo.y, lo.z, lo.w, hi.x, hi.y, hi.z, hi.w};
        float aw[8]; uint32_t pk[8]; uint32_t wsgnshuf = 0;
#pragma unroll
        for (int j = 0; j < 8; ++j) {
            uint32_t sb = __float_as_uint(w[j]) >> 31;
            wsgnshuf |= sb << shuf[j];
            aw[j] = fabsf(w[j]);
            uint32_t tw = (uint32_t)(2.0f * aw[j]);          // exact in {1,3,5}
            pk[j] = (tw << 13) | ((uint32_t)j << 10) | (1u << shuf[j]);
        }
        sWp[0][tid] = make_float2(aw[0], aw[1]);
        sWp[1][tid] = make_float2(aw[2], aw[3]);
        sWp[2][tid] = make_float2(aw[4], aw[5]);
        sWp[3][tid] = make_float2(aw[6], aw[7]);
#pragma unroll
        for (int i = 0; i < 4; ++i) sPK[i][tid] = pk[2 * i] | (pk[2 * i + 1] << 16);
        sMeta[tid] = wsgnshuf | ((uint32_t)(__popc(wsgnshuf) & 1) << 8);
        sSN[tid] = grid_norm[(size_t)tid * 256];
    }
    __syncthreads();

    const int lane = tid & 63, wid = tid >> 6;
    const int A  = blockIdx.x >> 3;       // [0,128): matrix quad-row
    const int Bh = blockIdx.x & 7;        // [0,8):   pair of quad-cols
    // wave wid = 2q+i handles matrix row 2A+i, cols 4Bh+2q+{0,1}
    const int rbase = (2 * A + (wid & 1)) * 32 + 4 * Bh + 2 * (wid >> 1);

    // ---- per-row setup (2 rows) ----
    double   xd[2][8]; double Sx[2];
    uint32_t sp1b[2], sp0sh[2], sp1sh[2], pp0[2], pp1[2];
#pragma unroll
    for (int s = 0; s < 2; ++s) {
        const float* xr = X + (size_t)(rbase + s) * 8;
        double acc = 0.0; uint32_t m1 = 0, m0s = 0, m1s = 0, p0 = 0, p1 = 0;
#pragma unroll
        for (int j = 0; j < 8; ++j) {
            float xf = xr[j]; double d = (double)xf;
            xd[s][j] = d; acc += d;
            uint32_t b0 = (xf < 0.0f) ? 1u : 0u;
            uint32_t b1 = (d < -0.25) ? 1u : 0u;
            m1 |= b1 << j; m0s |= b0 << shuf[j]; m1s |= b1 << shuf[j];
            p0 ^= b0; p1 ^= b1;
        }
        Sx[s] = acc; sp1b[s] = m1; sp0sh[s] = m0s; sp1sh[s] = m1s; pp0[s] = p0; pp1[s] = p1;
    }

    float bestS[2] = {-INFINITY, -INFINITY};
    int   bestC[2] = {0x7fffffff, 0x7fffffff};

#pragma unroll
    for (int k = 0; k < 4; ++k) {
        const int absi = lane + (k << 6);
        float2 w01 = sWp[0][absi], w23 = sWp[1][absi], w45 = sWp[2][absi], w67 = sWp[3][absi];
        float awf[8] = {w01.x, w01.y, w23.x, w23.y, w45.x, w45.y, w67.x, w67.y};
        uint32_t pw0 = sPK[0][absi], pw1 = sPK[1][absi], pw2 = sPK[2][absi], pw3 = sPK[3][absi];
        uint32_t pk16[8] = {pw0 & 0xFFFFu, pw0 >> 16, pw1 & 0xFFFFu, pw1 >> 16,
                            pw2 & 0xFFFFu, pw2 >> 16, pw3 & 0xFFFFu, pw3 >> 16};
        const uint32_t meta = sMeta[absi];
        const float    sN   = sSN[absi];
        const uint32_t wsh = meta & 0xFFu, wpar = (meta >> 8) & 1u;
        double wdA[8];
#pragma unroll
        for (int j = 0; j < 8; ++j) wdA[j] = (double)awf[j];

#pragma unroll
        for (int s = 0; s < 2; ++s) {
            double t0[8], t1[8];
#pragma unroll
            for (int j = 0; j < 8; ++j) {
                t0[j] = wdA[j] * xd[s][j];           // sign = sign(x_j)
                t1[j] = fma(t0[j], 4.0, wdA[j]);     // = 4*|w|*(x+0.25)
            }
            // ---- p = 0 ----
            {
                double Sab = ((fabs(t0[0]) + fabs(t0[1])) + (fabs(t0[2]) + fabs(t0[3])))
                           + ((fabs(t0[4]) + fabs(t0[5])) + (fabs(t0[6]) + fabs(t0[7])));
                double kk[8];
#pragma unroll
                for (int j = 0; j < 8; ++j) kk[j] = pay_abs(t0[j], pk16[j]);
                TournOut o = tourn8(kk);
                uint32_t sb1 = o.q1 & 0xFFu, sb2 = o.q2 & 0xFFu;
                uint32_t par = wpar ^ pp0[s];
                uint32_t seffb = wsh ^ sp0sh[s];
                double dA = par ? o.a1c : 0.0;
                double dB = par ? o.a2c : (o.a1c + o.a2c);
                uint32_t sbA = par ? sb1 : 0u;
                uint32_t sbB = par ? sb2 : (sb1 ^ sb2);
                { float f = (float)(Sab - 2.0 * dA);
                  cmp_keep(bestS[s], bestC[s], 2.0f * f - sN, (absi << 8) | (int)(seffb ^ sbA)); }
                { float f = (float)(Sab - 2.0 * dB);
                  cmp_keep(bestS[s], bestC[s], 2.0f * f - sN, (absi << 8) | (int)(seffb ^ sbB)); }
            }
            // ---- p = 1 (4x-scaled domain) ----
            {
                double Sab4 = ((fabs(t1[0]) + fabs(t1[1])) + (fabs(t1[2]) + fabs(t1[3])))
                            + ((fabs(t1[4]) + fabs(t1[5])) + (fabs(t1[6]) + fabs(t1[7])));
                double kk[8];
#pragma unroll
                for (int j = 0; j < 8; ++j) kk[j] = pay_abs(t1[j], pk16[j]);
                TournOut o = tourn8(kk);
                uint32_t sb1 = o.q1 & 0xFFu, sb2 = o.q2 & 0xFFu;
                uint32_t par = wpar ^ pp1[s];
                uint32_t seffb = wsh ^ sp1sh[s];
                double dA = par ? o.a1c : 0.0;
                double dB = par ? o.a2c : (o.a1c + o.a2c);
                uint32_t sbA = par ? sb1 : 0u;
                uint32_t sbB = par ? sb2 : (sb1 ^ sb2);
                float W0 = ((((sp1b[s] >> 0) & 1) ? -awf[0] : awf[0]) + (((sp1b[s] >> 1) & 1) ? -awf[1] : awf[1]))
                         + ((((sp1b[s] >> 2) & 1) ? -awf[2] : awf[2]) + (((sp1b[s] >> 3) & 1) ? -awf[3] : awf[3]))
                         + (((((sp1b[s] >> 4) & 1) ? -awf[4] : awf[4]) + (((sp1b[s] >> 5) & 1) ? -awf[5] : awf[5]))
                         +  ((((sp1b[s] >> 6) & 1) ? -awf[6] : awf[6]) + (((sp1b[s] >> 7) & 1) ? -awf[7] : awf[7])));
                uint32_t j1 = (o.q1 >> 10) & 7u, j2 = (o.q2 >> 10) & 7u;
                float w1f = 0.5f * (float)(o.q1 >> 13);
                float w2f = 0.5f * (float)(o.q2 >> 13);
                float sw1 = ((sp1b[s] >> j1) & 1) ? -w1f : w1f;
                float sw2 = ((sp1b[s] >> j2) & 1) ? -w2f : w2f;
                float swA = par ? sw1 : 0.0f;
                float swB = par ? sw2 : (sw1 + sw2);
                {
                    float Wc = W0 - 2.0f * swA;                    // exact f32
                    double E = (Sab4 - 2.0 * dA) - ((double)Wc + Sx[s]);
                    float f = (float)(0.25 * E);
                    float gnv = (sN - 0.5f * Wc) + 0.5f;           // exact f32
                    cmp_keep(bestS[s], bestC[s], 2.0f * f - gnv,
                             (absi << 8) | (int)((seffb ^ sbA) ^ 1u));
                }
                {
                    float Wc = W0 - 2.0f * swB;
                    double E = (Sab4 - 2.0 * dB) - ((double)Wc + Sx[s]);
                    float f = (float)(0.25 * E);
                    float gnv = (sN - 0.5f * Wc) + 0.5f;
                    cmp_keep(bestS[s], bestC[s], 2.0f * f - gnv,
                             (absi << 8) | (int)((seffb ^ sbB) ^ 1u));
                }
            }
        }
    }

    // ---- two interleaved wave reduces (ties -> lower c) ----
#pragma unroll
    for (int off = 32; off > 0; off >>= 1) {
        float s0 = __shfl_xor(bestS[0], off); int c0 = __shfl_xor(bestC[0], off);
        float s1 = __shfl_xor(bestS[1], off); int c1 = __shfl_xor(bestC[1], off);
        cmp_keep(bestS[0], bestC[0], s0, c0);
        cmp_keep(bestS[1], bestC[1], s1, c1);
    }

    if (lane < 2) {                       // lane s handles row rbase+s
        const int s = lane;
        const int c = bestC[s];
        const int row = rbase + s;
        const float4* gg = reinterpret_cast<const float4*>(grid + (size_t)c * 8);
        float4* v4 = reinterpret_cast<float4*>(out + (size_t)row * 8);
        v4[0] = gg[0]; v4[1] = gg[1];
        out[65536 + row] = (float)c;
        sC[wid][s] = c;
    }
    __syncthreads();

    if (tid < 2) {                        // 2 pack quads per block
        const int q = tid;
        const uint32_t e00 = (uint32_t)sC[2 * q + 0][0];
        const uint32_t e10 = (uint32_t)sC[2 * q + 1][0];
        const uint32_t e01 = (uint32_t)sC[2 * q + 0][1];
        const uint32_t e11 = (uint32_t)sC[2 * q + 1][1];
        const uint32_t abs32 = (e00 >> 8) | ((e10 >> 8) << 8)
                             | ((e01 >> 8) << 16) | ((e11 >> 8) << 24);
        const int Bq = 2 * Bh + q;
        const int f = ((A >> 3) << 7) | ((Bq >> 2) << 5) | ((A & 7) << 2) | (Bq & 3);
        out[73728 + f] = (float)(int32_t)abs32;   // int32-wrap: only abs32 survives
    }
}

extern "C" void kernel_launch(void* const* d_in, const int* in_sizes, int n_in,
                              void* d_out, int out_size, void* d_ws, size_t ws_size,
                              hipStream_t stream)
{
    const float* X    = (const float*)d_in[0];
    const float* grid = (const float*)d_in[1];
    const float* gn   = (const float*)d_in[2];
    e8p_fused2<<<1024, 256, 0, stream>>>(X, grid, gn, (float*)d_out);
}

// Round 8
// 76.522 us; speedup vs baseline: 1.0830x; 1.0830x over previous
//
#include <hip/hip_runtime.h>
#include <stdint.h>
#include <math.h>

// E8P codebook argmax (fused3) = R4 geometry + R6 validated ingredients.
// Per (absi,p): t_j = |w_j|*(x_j+0.25p); p=1 handled in 4x-scaled domain via
// t1 = fma(t0,4,|w|).  Best/2nd-best even-parity sign flips closed-form via a
// payload-packed f64 (min,2nd-min) tournament ((2|w|,j,shufbit) in low 16
// mantissa bits, 2^-36 rel perturbation).  score = 2*fl32(f64 dot) - gn with
// gn reconstructed exactly in f32; ties -> lower c.
// Output float32-flat: [vals 65536 | idxs 8192 | packed-as-int32-wrap 2048].

__device__ __forceinline__ void cmp_keep(float& bs, int& bc, float s, int c) {
    if (s > bs || (s == bs && c < bc)) { bs = s; bc = c; }
}

__device__ __forceinline__ double pay_abs(double t, uint32_t pk16) {
    long long ll = __double_as_longlong(t) & 0x7FFFFFFFFFFF0000ll;
    return __longlong_as_double(ll | (long long)pk16);
}

struct TournOut { double a1c, a2c; uint32_t q1, q2; };

__device__ __forceinline__ TournOut tourn8(const double kk[8]) {
    double m01 = fmin(kk[0], kk[1]), x01 = fmax(kk[0], kk[1]);
    double m23 = fmin(kk[2], kk[3]), x23 = fmax(kk[2], kk[3]);
    double m45 = fmin(kk[4], kk[5]), x45 = fmax(kk[4], kk[5]);
    double m67 = fmin(kk[6], kk[7]), x67 = fmax(kk[6], kk[7]);
    double mA = fmin(m01, m23), sA = fmin(fmax(m01, m23), fmin(x01, x23));
    double mB = fmin(m45, m67), sB = fmin(fmax(m45, m67), fmin(x45, x67));
    double m1 = fmin(mA, mB),   m2 = fmin(fmax(mA, mB), fmin(sA, sB));
    long long b1 = __double_as_longlong(m1);
    long long b2 = __double_as_longlong(m2);
    TournOut o;
    o.a1c = __longlong_as_double(b1 & ~0xFFFFll);
    o.a2c = __longlong_as_double(b2 & ~0xFFFFll);
    o.q1 = (uint32_t)b1 & 0xFFFFu;
    o.q2 = (uint32_t)b2 & 0xFFFFu;
    return o;
}

__global__ __launch_bounds__(256) void e8p_fused3(
    const float* __restrict__ X,
    const float* __restrict__ grid,
    const float* __restrict__ grid_norm,
    float* __restrict__ out)
{
    __shared__ float2   sWp[4][256];    // |w| element-pairs, transposed (<=2-way: free)
    __shared__ uint32_t sPK[4][256];    // payload u16-pairs, transposed (1-way)
    __shared__ uint32_t sMeta[256];     // wsgnshuf | (wpar<<8)
    __shared__ float    sSN[256];
    __shared__ int      sC[4];

    const int tid = threadIdx.x;
    const int shuf[8] = {0, 4, 1, 5, 2, 6, 3, 7};

    {   // ---- stage per-absi tables (tid == absi) ----
        const float4* g4 = reinterpret_cast<const float4*>(grid + (size_t)tid * 2048);
        float4 lo = g4[0], hi = g4[1];
        float w[8] = {lo.x, lo.y, lo.z, lo.w, hi.x, hi.y, hi.z, hi.w};
        float aw[8]; uint32_t pk[8]; uint32_t wsgnshuf = 0;
#pragma unroll
        for (int j = 0; j < 8; ++j) {
            uint32_t sb = __float_as_uint(w[j]) >> 31;
            wsgnshuf |= sb << shuf[j];
            aw[j] = fabsf(w[j]);
            uint32_t tw = (uint32_t)(2.0f * aw[j]);          // exact in {1,3,5,7}
            pk[j] = (tw << 13) | ((uint32_t)j << 10) | (1u << shuf[j]);
        }
        sWp[0][tid] = make_float2(aw[0], aw[1]);
        sWp[1][tid] = make_float2(aw[2], aw[3]);
        sWp[2][tid] = make_float2(aw[4], aw[5]);
        sWp[3][tid] = make_float2(aw[6], aw[7]);
#pragma unroll
        for (int i = 0; i < 4; ++i) sPK[i][tid] = pk[2 * i] | (pk[2 * i + 1] << 16);
        sMeta[tid] = wsgnshuf | ((uint32_t)(__popc(wsgnshuf) & 1) << 8);
        sSN[tid] = grid_norm[(size_t)tid * 256];
    }
    __syncthreads();

    const int lane = tid & 63, wid = tid >> 6;
    const int A = blockIdx.x >> 4, B = blockIdx.x & 15;
    const int row = A * 64 + (wid >> 1) * 32 + B * 2 + (wid & 1);   // R4-validated

    // ---- per-row setup ----
    const float* xr = X + (size_t)row * 8;
    double xd[8], Sx = 0.0;
    uint32_t sp1b = 0, sp0sh = 0, sp1sh = 0, pp0 = 0, pp1 = 0;
#pragma unroll
    for (int j = 0; j < 8; ++j) {
        float xf = xr[j]; double d = (double)xf;
        xd[j] = d; Sx += d;
        uint32_t b0 = (xf < 0.0f) ? 1u : 0u;
        uint32_t b1 = (d < -0.25) ? 1u : 0u;
        sp1b |= b1 << j;
        sp0sh |= b0 << shuf[j]; sp1sh |= b1 << shuf[j];
        pp0 ^= b0; pp1 ^= b1;
    }

    float bestS = -INFINITY; int bestC = 0x7fffffff;

    for (int k = 0; k < 4; ++k) {
        const int absi = lane + (k << 6);
        float2 w01 = sWp[0][absi], w23 = sWp[1][absi], w45 = sWp[2][absi], w67 = sWp[3][absi];
        float awf[8] = {w01.x, w01.y, w23.x, w23.y, w45.x, w45.y, w67.x, w67.y};
        uint32_t pw0 = sPK[0][absi], pw1 = sPK[1][absi], pw2 = sPK[2][absi], pw3 = sPK[3][absi];
        uint32_t pk16[8] = {pw0 & 0xFFFFu, pw0 >> 16, pw1 & 0xFFFFu, pw1 >> 16,
                            pw2 & 0xFFFFu, pw2 >> 16, pw3 & 0xFFFFu, pw3 >> 16};
        const uint32_t meta = sMeta[absi];
        const float    sN   = sSN[absi];
        const uint32_t wsh = meta & 0xFFu, wpar = (meta >> 8) & 1u;

        // products (|w| converted on the fly; no stored f64 w array)
        double kk0[8], t1[8];
#pragma unroll
        for (int j = 0; j < 8; ++j) {
            double wd = (double)awf[j];
            double t0 = wd * xd[j];              // exact (<=27-bit product)
            t1[j]  = fma(t0, 4.0, wd);           // 4*|w|*(x+0.25), ~exact (R6-validated)
            kk0[j] = pay_abs(t0, pk16[j]);
        }

        // ---- p = 0 ----
        {
            double Sab = ((fabs(kk0[0]) + fabs(kk0[1])) + (fabs(kk0[2]) + fabs(kk0[3])))
                       + ((fabs(kk0[4]) + fabs(kk0[5])) + (fabs(kk0[6]) + fabs(kk0[7])));
            // NOTE: kk0 == |t0| with low-16 payload (2^-36 rel) — same numeric
            // class as the validated R6 Sab (payload perturbs below all
            // decision scales; final f32 round absorbs it).
            TournOut o = tourn8(kk0);
            uint32_t sb1 = o.q1 & 0xFFu, sb2 = o.q2 & 0xFFu;
            uint32_t par = wpar ^ pp0;
            uint32_t seffb = wsh ^ sp0sh;
            double dA = par ? o.a1c : 0.0;
            double dB = par ? o.a2c : (o.a1c + o.a2c);
            uint32_t sbA = par ? sb1 : 0u;
            uint32_t sbB = par ? sb2 : (sb1 ^ sb2);
            { float f = (float)(Sab - 2.0 * dA);
              cmp_keep(bestS, bestC, 2.0f * f - sN, (absi << 8) | (int)(seffb ^ sbA)); }
            { float f = (float)(Sab - 2.0 * dB);
              cmp_keep(bestS, bestC, 2.0f * f - sN, (absi << 8) | (int)(seffb ^ sbB)); }
        }
        // ---- p = 1 (4x-scaled domain) ----
        {
            double kk1[8];
#pragma unroll
            for (int j = 0; j < 8; ++j) kk1[j] = pay_abs(t1[j], pk16[j]);
            double Sab4 = ((fabs(kk1[0]) + fabs(kk1[1])) + (fabs(kk1[2]) + fabs(kk1[3])))
                        + ((fabs(kk1[4]) + fabs(kk1[5])) + (fabs(kk1[6]) + fabs(kk1[7])));
            TournOut o = tourn8(kk1);
            uint32_t sb1 = o.q1 & 0xFFu, sb2 = o.q2 & 0xFFu;
            uint32_t par = wpar ^ pp1;
            uint32_t seffb = wsh ^ sp1sh;
            double dA = par ? o.a1c : 0.0;
            double dB = par ? o.a2c : (o.a1c + o.a2c);
            uint32_t sbA = par ? sb1 : 0u;
            uint32_t sbB = par ? sb2 : (sb1 ^ sb2);
            float W0 = ((((sp1b >> 0) & 1) ? -awf[0] : awf[0]) + (((sp1b >> 1) & 1) ? -awf[1] : awf[1]))
                     + ((((sp1b >> 2) & 1) ? -awf[2] : awf[2]) + (((sp1b >> 3) & 1) ? -awf[3] : awf[3]))
                     + (((((sp1b >> 4) & 1) ? -awf[4] : awf[4]) + (((sp1b >> 5) & 1) ? -awf[5] : awf[5]))
                     +  ((((sp1b >> 6) & 1) ? -awf[6] : awf[6]) + (((sp1b >> 7) & 1) ? -awf[7] : awf[7])));
            uint32_t j1 = (o.q1 >> 10) & 7u, j2 = (o.q2 >> 10) & 7u;
            float w1f = 0.5f * (float)(o.q1 >> 13);
            float w2f = 0.5f * (float)(o.q2 >> 13);
            float sw1 = ((sp1b >> j1) & 1) ? -w1f : w1f;
            float sw2 = ((sp1b >> j2) & 1) ? -w2f : w2f;
            float swA = par ? sw1 : 0.0f;
            float swB = par ? sw2 : (sw1 + sw2);
            {
                float Wc = W0 - 2.0f * swA;                    // exact f32
                double E = (Sab4 - 2.0 * dA) - ((double)Wc + Sx);
                float f = (float)(0.25 * E);
                float gnv = (sN - 0.5f * Wc) + 0.5f;           // exact f32
                cmp_keep(bestS, bestC, 2.0f * f - gnv,
                         (absi << 8) | (int)((seffb ^ sbA) ^ 1u));
            }
            {
                float Wc = W0 - 2.0f * swB;
                double E = (Sab4 - 2.0 * dB) - ((double)Wc + Sx);
                float f = (float)(0.25 * E);
                float gnv = (sN - 0.5f * Wc) + 0.5f;
                cmp_keep(bestS, bestC, 2.0f * f - gnv,
                         (absi << 8) | (int)((seffb ^ sbB) ^ 1u));
            }
        }
    }

    // ---- wave reduce (ties -> lower c) ----
#pragma unroll
    for (int off = 32; off > 0; off >>= 1) {
        float s2 = __shfl_xor(bestS, off);
        int   c2 = __shfl_xor(bestC, off);
        cmp_keep(bestS, bestC, s2, c2);
    }

    if (lane == 0) {
        const int c = bestC;
        const float4* gg = reinterpret_cast<const float4*>(grid + (size_t)c * 8);
        float4* v4 = reinterpret_cast<float4*>(out + (size_t)row * 8);
        v4[0] = gg[0]; v4[1] = gg[1];
        out[65536 + row] = (float)c;
        sC[wid] = c;
    }
    __syncthreads();

    if (tid == 0) {   // fused pack: quad (A,B); waves are (i,j) = (wid>>1, wid&1)
        const uint32_t e00 = (uint32_t)sC[0], e01 = (uint32_t)sC[1];
        const uint32_t e10 = (uint32_t)sC[2], e11 = (uint32_t)sC[3];
        const uint32_t abs32 = (e00 >> 8) | ((e10 >> 8) << 8)
                             | ((e01 >> 8) << 16) | ((e11 >> 8) << 24);
        const int f = ((A >> 3) << 7) | ((B >> 2) << 5) | ((A & 7) << 2) | (B & 3);
        out[73728 + f] = (float)(int32_t)abs32;   // int32-wrap: only abs32 survives
    }
}

extern "C" void kernel_launch(void* const* d_in, const int* in_sizes, int n_in,
                              void* d_out, int out_size, void* d_ws, size_t ws_size,
                              hipStream_t stream)
{
    const float* X    = (const float*)d_in[0];
    const float* grid = (const float*)d_in[1];
    const float* gn   = (const float*)d_in[2];
    e8p_fused3<<<2048, 256, 0, stream>>>(X, grid, gn, (float*)d_out);
}

// Round 10
// 71.348 us; speedup vs baseline: 1.1615x; 1.0725x over previous
//
#include <hip/hip_runtime.h>
#include <stdint.h>
#include <math.h>

// E8P codebook argmax (screen) = f32 approximate screening + exact f64
// re-evaluation of survivors.  Exact path is bit-identical to fused3
// (validated 3x, absmax 0.0).  Screen soundness: fl32 is monotone; approx
// pair-score tracks exact score within ~1e-4 (bounded), survivors kept at
// eps=2e-3.  p=1 approx uses the Wc-cancellation identity:
//   score_p1 = 0.5*(Sab4 - 2*flips) - 0.5*Sx - sN - 0.5.
// Output float32-flat: [vals 65536 | idxs 8192 | packed-as-int32-wrap 2048].

#define EPS_SCREEN 2.0e-3f

__device__ __forceinline__ void cmp_keep(float& bs, int& bc, float s, int c) {
    if (s > bs || (s == bs && c < bc)) { bs = s; bc = c; }
}

struct TournOut { double a1c, a2c; uint32_t q1, q2; };

__device__ __forceinline__ TournOut tourn8(const double kk[8]) {
    double m01 = fmin(kk[0], kk[1]), x01 = fmax(kk[0], kk[1]);
    double m23 = fmin(kk[2], kk[3]), x23 = fmax(kk[2], kk[3]);
    double m45 = fmin(kk[4], kk[5]), x45 = fmax(kk[4], kk[5]);
    double m67 = fmin(kk[6], kk[7]), x67 = fmax(kk[6], kk[7]);
    double mA = fmin(m01, m23), sA = fmin(fmax(m01, m23), fmin(x01, x23));
    double mB = fmin(m45, m67), sB = fmin(fmax(m45, m67), fmin(x45, x67));
    double m1 = fmin(mA, mB),   m2 = fmin(fmax(mA, mB), fmin(sA, sB));
    long long b1 = __double_as_longlong(m1);
    long long b2 = __double_as_longlong(m2);
    TournOut o;
    o.a1c = __longlong_as_double(b1 & ~0xFFFFll);
    o.a2c = __longlong_as_double(b2 & ~0xFFFFll);
    o.q1 = (uint32_t)b1 & 0xFFFFu;
    o.q2 = (uint32_t)b2 & 0xFFFFu;
    return o;
}

// (min, 2nd-min) of |a[0..7]| — values only, f32
__device__ __forceinline__ float2 t8v(const float a[8]) {
    float m01 = fminf(fabsf(a[0]), fabsf(a[1])), x01 = fmaxf(fabsf(a[0]), fabsf(a[1]));
    float m23 = fminf(fabsf(a[2]), fabsf(a[3])), x23 = fmaxf(fabsf(a[2]), fabsf(a[3]));
    float m45 = fminf(fabsf(a[4]), fabsf(a[5])), x45 = fmaxf(fabsf(a[4]), fabsf(a[5]));
    float m67 = fminf(fabsf(a[6]), fabsf(a[7])), x67 = fmaxf(fabsf(a[6]), fabsf(a[7]));
    float mA = fminf(m01, m23), sA = fminf(fmaxf(m01, m23), fminf(x01, x23));
    float mB = fminf(m45, m67), sB = fminf(fmaxf(m45, m67), fminf(x45, x67));
    return make_float2(fminf(mA, mB), fminf(fmaxf(mA, mB), fminf(sA, sB)));
}

__global__ __launch_bounds__(256) void e8p_screen(
    const float* __restrict__ X,
    const float* __restrict__ grid,
    const float* __restrict__ grid_norm,
    float* __restrict__ out)
{
    __shared__ float2   sWp[4][256];
    __shared__ uint32_t sPK[4][256];
    __shared__ uint32_t sMeta[256];
    __shared__ float    sSN[256];
    __shared__ int      sC[4];

    const int tid = threadIdx.x;
    const int shuf[8] = {0, 4, 1, 5, 2, 6, 3, 7};

    {   // ---- stage per-absi tables (tid == absi) — verbatim fused3 ----
        const float4* g4 = reinterpret_cast<const float4*>(grid + (size_t)tid * 2048);
        float4 lo = g4[0], hi = g4[1];
        float w[8] = {lo.x, lo.y, lo.z, lo.w, hi.x, hi.y, hi.z, hi.w};
        float aw[8]; uint32_t pk[8]; uint32_t wsgnshuf = 0;
#pragma unroll
        for (int j = 0; j < 8; ++j) {
            uint32_t sb = __float_as_uint(w[j]) >> 31;
            wsgnshuf |= sb << shuf[j];
            aw[j] = fabsf(w[j]);
            uint32_t tw = (uint32_t)(2.0f * aw[j]);          // exact in {1,3,5,7}
            pk[j] = (tw << 13) | ((uint32_t)j << 10) | (1u << shuf[j]);
        }
        sWp[0][tid] = make_float2(aw[0], aw[1]);
        sWp[1][tid] = make_float2(aw[2], aw[3]);
        sWp[2][tid] = make_float2(aw[4], aw[5]);
        sWp[3][tid] = make_float2(aw[6], aw[7]);
#pragma unroll
        for (int i = 0; i < 4; ++i) sPK[i][tid] = pk[2 * i] | (pk[2 * i + 1] << 16);
        sMeta[tid] = wsgnshuf | ((uint32_t)(__popc(wsgnshuf) & 1) << 8);
        sSN[tid] = grid_norm[(size_t)tid * 256];
    }
    __syncthreads();

    const int lane = tid & 63, wid = tid >> 6;
    const int A = blockIdx.x >> 4, B = blockIdx.x & 15;
    const int row = A * 64 + (wid >> 1) * 32 + B * 2 + (wid & 1);

    // ---- per-row setup ----
    const float* xr = X + (size_t)row * 8;
    float  xf[8]; double xd[8], Sx = 0.0;
    uint32_t sp1b = 0, sp0sh = 0, sp1sh = 0, pp0 = 0, pp1 = 0;
#pragma unroll
    for (int j = 0; j < 8; ++j) {
        float f = xr[j]; double d = (double)f;
        xf[j] = f; xd[j] = d; Sx += d;
        uint32_t b0 = (f < 0.0f) ? 1u : 0u;
        uint32_t b1 = (d < -0.25) ? 1u : 0u;
        sp1b |= b1 << j;
        sp0sh |= b0 << shuf[j]; sp1sh |= b1 << shuf[j];
        pp0 ^= b0; pp1 ^= b1;
    }
    const float c1row = 0.5f * (float)Sx + 0.5f;   // p1 approx constant

    // ---------- approx phase (f32, values-only) ----------
    float apx[8];
#pragma unroll
    for (int k = 0; k < 4; ++k) {
        const int absi = lane + (k << 6);
        float2 w01 = sWp[0][absi], w23 = sWp[1][absi], w45 = sWp[2][absi], w67 = sWp[3][absi];
        float awf[8] = {w01.x, w01.y, w23.x, w23.y, w45.x, w45.y, w67.x, w67.y};
        const float sN = sSN[absi];
        const uint32_t wpar = (sMeta[absi] >> 8) & 1u;
        float t0s[8], t1s[8];
#pragma unroll
        for (int j = 0; j < 8; ++j) { t0s[j] = awf[j] * xf[j]; t1s[j] = fmaf(t0s[j], 4.0f, awf[j]); }
        float S0 = ((fabsf(t0s[0]) + fabsf(t0s[1])) + (fabsf(t0s[2]) + fabsf(t0s[3])))
                 + ((fabsf(t0s[4]) + fabsf(t0s[5])) + (fabsf(t0s[6]) + fabsf(t0s[7])));
        float S4 = ((fabsf(t1s[0]) + fabsf(t1s[1])) + (fabsf(t1s[2]) + fabsf(t1s[3])))
                 + ((fabsf(t1s[4]) + fabsf(t1s[5])) + (fabsf(t1s[6]) + fabsf(t1s[7])));
        float2 mm0 = t8v(t0s);
        float2 mm1 = t8v(t1s);
        {   uint32_t par = wpar ^ pp0;
            float dA = par ? mm0.x : 0.0f, dB = par ? mm0.y : (mm0.x + mm0.y);
            float a = 2.0f * (S0 - 2.0f * dA) - sN;
            float b = 2.0f * (S0 - 2.0f * dB) - sN;
            apx[2 * k] = fmaxf(a, b); }
        {   uint32_t par = wpar ^ pp1;
            float dA = par ? mm1.x : 0.0f, dB = par ? mm1.y : (mm1.x + mm1.y);
            float a = 0.5f * (S4 - 2.0f * dA) - sN - c1row;
            float b = 0.5f * (S4 - 2.0f * dB) - sN - c1row;
            apx[2 * k + 1] = fmaxf(a, b); }
    }

    float lm = apx[0];
#pragma unroll
    for (int i = 1; i < 8; ++i) lm = fmaxf(lm, apx[i]);
    const float thr = lm - EPS_SCREEN;
    uint32_t smask = 0;
#pragma unroll
    for (int i = 0; i < 8; ++i) smask |= (apx[i] >= thr ? 1u : 0u) << i;

    float bestS = -INFINITY; int bestC = 0x7fffffff;

    // ---------- exact phase (fused3-identical numerics, survivors only) ----------
    while (__any(smask != 0)) {
        if (smask) {
            const int slot = __ffs((int)smask) - 1;
            smask &= smask - 1;
            const int k = slot >> 1;
            const uint32_t p = (uint32_t)(slot & 1);
            const int absi = lane + (k << 6);

            float2 w01 = sWp[0][absi], w23 = sWp[1][absi], w45 = sWp[2][absi], w67 = sWp[3][absi];
            float awf[8] = {w01.x, w01.y, w23.x, w23.y, w45.x, w45.y, w67.x, w67.y};
            uint32_t pw0 = sPK[0][absi], pw1 = sPK[1][absi], pw2 = sPK[2][absi], pw3 = sPK[3][absi];
            uint32_t pk16[8] = {pw0 & 0xFFFFu, pw0 >> 16, pw1 & 0xFFFFu, pw1 >> 16,
                                pw2 & 0xFFFFu, pw2 >> 16, pw3 & 0xFFFFu, pw3 >> 16};
            const uint32_t meta = sMeta[absi];
            const float    sN   = sSN[absi];
            const uint32_t wsh = meta & 0xFFu, wpar = (meta >> 8) & 1u;

            double kk[8];
#pragma unroll
            for (int j = 0; j < 8; ++j) {
                double wd = (double)awf[j];
                double t0 = wd * xd[j];                       // exact
                double tt = p ? fma(t0, 4.0, wd) : t0;        // fused3-identical
                long long ll = __double_as_longlong(tt) & 0x7FFFFFFFFFFF0000ll;
                kk[j] = __longlong_as_double(ll | (long long)pk16[j]);
            }
            double Sab = ((kk[0] + kk[1]) + (kk[2] + kk[3]))
                       + ((kk[4] + kk[5]) + (kk[6] + kk[7]));  // == fused3 (kk >= 0)

            TournOut o = tourn8(kk);
            uint32_t sb1 = o.q1 & 0xFFu, sb2 = o.q2 & 0xFFu;
            uint32_t par = wpar ^ (p ? pp1 : pp0);
            uint32_t seffb = wsh ^ (p ? sp1sh : sp0sh);
            double dA = par ? o.a1c : 0.0;
            double dB = par ? o.a2c : (o.a1c + o.a2c);
            uint32_t sbA = par ? sb1 : 0u;
            uint32_t sbB = par ? sb2 : (sb1 ^ sb2);

            // W-path (meaningful only for p=1; selected out for p=0)
            float W0 = ((((sp1b >> 0) & 1) ? -awf[0] : awf[0]) + (((sp1b >> 1) & 1) ? -awf[1] : awf[1]))
                     + ((((sp1b >> 2) & 1) ? -awf[2] : awf[2]) + (((sp1b >> 3) & 1) ? -awf[3] : awf[3]))
                     + (((((sp1b >> 4) & 1) ? -awf[4] : awf[4]) + (((sp1b >> 5) & 1) ? -awf[5] : awf[5]))
                     +  ((((sp1b >> 6) & 1) ? -awf[6] : awf[6]) + (((sp1b >> 7) & 1) ? -awf[7] : awf[7])));
            uint32_t j1 = (o.q1 >> 10) & 7u, j2 = (o.q2 >> 10) & 7u;
            float w1f = 0.5f * (float)(o.q1 >> 13);
            float w2f = 0.5f * (float)(o.q2 >> 13);
            float sw1 = ((sp1b >> j1) & 1) ? -w1f : w1f;
            float sw2 = ((sp1b >> j2) & 1) ? -w2f : w2f;
            float swA = par ? sw1 : 0.0f;
            float swB = par ? sw2 : (sw1 + sw2);
            float WcA = W0 - 2.0f * swA;
            float WcB = W0 - 2.0f * swB;

            {   double EA = (Sab - 2.0 * dA) - (p ? ((double)WcA + Sx) : 0.0);
                float fA = (float)(p ? 0.25 * EA : EA);
                float gnvA = p ? ((sN - 0.5f * WcA) + 0.5f) : sN;
                cmp_keep(bestS, bestC, 2.0f * fA - gnvA,
                         (absi << 8) | (int)(seffb ^ sbA ^ p)); }
            {   double EB = (Sab - 2.0 * dB) - (p ? ((double)WcB + Sx) : 0.0);
                float fB = (float)(p ? 0.25 * EB : EB);
                float gnvB = p ? ((sN - 0.5f * WcB) + 0.5f) : sN;
                cmp_keep(bestS, bestC, 2.0f * fB - gnvB,
                         (absi << 8) | (int)(seffb ^ sbB ^ p)); }
        }
    }

    // ---- wave reduce (ties -> lower c) ----
#pragma unroll
    for (int off = 32; off > 0; off >>= 1) {
        float s2 = __shfl_xor(bestS, off);
        int   c2 = __shfl_xor(bestC, off);
        cmp_keep(bestS, bestC, s2, c2);
    }

    if (lane == 0) {
        const int c = bestC;
        const float4* gg = reinterpret_cast<const float4*>(grid + (size_t)c * 8);
        float4* v4 = reinterpret_cast<float4*>(out + (size_t)row * 8);
        v4[0] = gg[0]; v4[1] = gg[1];
        out[65536 + row] = (float)c;
        sC[wid] = c;
    }
    __syncthreads();

    if (tid == 0) {   // fused pack: quad (A,B); waves are (i,j) = (wid>>1, wid&1)
        const uint32_t e00 = (uint32_t)sC[0], e01 = (uint32_t)sC[1];
        const uint32_t e10 = (uint32_t)sC[2], e11 = (uint32_t)sC[3];
        const uint32_t abs32 = (e00 >> 8) | ((e10 >> 8) << 8)
                             | ((e01 >> 8) << 16) | ((e11 >> 8) << 24);
        const int f = ((A >> 3) << 7) | ((B >> 2) << 5) | ((A & 7) << 2) | (B & 3);
        out[73728 + f] = (float)(int32_t)abs32;   // int32-wrap: only abs32 survives
    }
}

extern "C" void kernel_launch(void* const* d_in, const int* in_sizes, int n_in,
                              void* d_out, int out_size, void* d_ws, size_t ws_size,
                              hipStream_t stream)
{
    const float* X    = (const float*)d_in[0];
    const float* grid = (const float*)d_in[1];
    const float* gn   = (const float*)d_in[2];
    e8p_screen<<<2048, 256, 0, stream>>>(X, grid, gn, (float*)d_out);
}

// Round 11
// 70.141 us; speedup vs baseline: 1.1815x; 1.0172x over previous
//
#include <hip/hip_runtime.h>
#include <stdint.h>
#include <math.h>

// E8P codebook argmax (screen2): f32 approximate screening + exact f64
// re-evaluation of survivors.  Exact path byte-identical to R10 (validated,
// absmax 0.0).  Approx cut vs R10: per (absi,p) candidate A always dominates
// candidate B in exact arithmetic (d_A <= d_B; Wc cancels for p=1), so the
// pair bound needs only min1 — no 2nd-min tournament.
//   apx_p0 = 2*S0 - (par ? 4*min1 : 0) - sN
//   apx_p1 = 0.5*S4 - (par ? min1 : 0) - sN - (0.5*Sx + 0.5)
// Survivors kept at eps=2e-3 (error ~1e-4 => 20x margin).
// Output float32-flat: [vals 65536 | idxs 8192 | packed-as-int32-wrap 2048].

#define EPS_SCREEN 2.0e-3f

__device__ __forceinline__ void cmp_keep(float& bs, int& bc, float s, int c) {
    if (s > bs || (s == bs && c < bc)) { bs = s; bc = c; }
}

struct TournOut { double a1c, a2c; uint32_t q1, q2; };

__device__ __forceinline__ TournOut tourn8(const double kk[8]) {
    double m01 = fmin(kk[0], kk[1]), x01 = fmax(kk[0], kk[1]);
    double m23 = fmin(kk[2], kk[3]), x23 = fmax(kk[2], kk[3]);
    double m45 = fmin(kk[4], kk[5]), x45 = fmax(kk[4], kk[5]);
    double m67 = fmin(kk[6], kk[7]), x67 = fmax(kk[6], kk[7]);
    double mA = fmin(m01, m23), sA = fmin(fmax(m01, m23), fmin(x01, x23));
    double mB = fmin(m45, m67), sB = fmin(fmax(m45, m67), fmin(x45, x67));
    double m1 = fmin(mA, mB),   m2 = fmin(fmax(mA, mB), fmin(sA, sB));
    long long b1 = __double_as_longlong(m1);
    long long b2 = __double_as_longlong(m2);
    TournOut o;
    o.a1c = __longlong_as_double(b1 & ~0xFFFFll);
    o.a2c = __longlong_as_double(b2 & ~0xFFFFll);
    o.q1 = (uint32_t)b1 & 0xFFFFu;
    o.q2 = (uint32_t)b2 & 0xFFFFu;
    return o;
}

// min of |a[0..7]| — values only, f32 (abs folds into VOP3 input modifiers)
__device__ __forceinline__ float t8min(const float a[8]) {
    float m01 = fminf(fabsf(a[0]), fabsf(a[1]));
    float m23 = fminf(fabsf(a[2]), fabsf(a[3]));
    float m45 = fminf(fabsf(a[4]), fabsf(a[5]));
    float m67 = fminf(fabsf(a[6]), fabsf(a[7]));
    return fminf(fminf(m01, m23), fminf(m45, m67));
}

__global__ __launch_bounds__(256) void e8p_screen2(
    const float* __restrict__ X,
    const float* __restrict__ grid,
    const float* __restrict__ grid_norm,
    float* __restrict__ out)
{
    __shared__ float2   sWp[4][256];
    __shared__ uint32_t sPK[4][256];
    __shared__ uint32_t sMeta[256];
    __shared__ float    sSN[256];
    __shared__ int      sC[4];

    const int tid = threadIdx.x;
    const int shuf[8] = {0, 4, 1, 5, 2, 6, 3, 7};

    {   // ---- stage per-absi tables (tid == absi) — verbatim validated ----
        const float4* g4 = reinterpret_cast<const float4*>(grid + (size_t)tid * 2048);
        float4 lo = g4[0], hi = g4[1];
        float w[8] = {lo.x, lo.y, lo.z, lo.w, hi.x, hi.y, hi.z, hi.w};
        float aw[8]; uint32_t pk[8]; uint32_t wsgnshuf = 0;
#pragma unroll
        for (int j = 0; j < 8; ++j) {
            uint32_t sb = __float_as_uint(w[j]) >> 31;
            wsgnshuf |= sb << shuf[j];
            aw[j] = fabsf(w[j]);
            uint32_t tw = (uint32_t)(2.0f * aw[j]);          // exact in {1,3,5,7}
            pk[j] = (tw << 13) | ((uint32_t)j << 10) | (1u << shuf[j]);
        }
        sWp[0][tid] = make_float2(aw[0], aw[1]);
        sWp[1][tid] = make_float2(aw[2], aw[3]);
        sWp[2][tid] = make_float2(aw[4], aw[5]);
        sWp[3][tid] = make_float2(aw[6], aw[7]);
#pragma unroll
        for (int i = 0; i < 4; ++i) sPK[i][tid] = pk[2 * i] | (pk[2 * i + 1] << 16);
        sMeta[tid] = wsgnshuf | ((uint32_t)(__popc(wsgnshuf) & 1) << 8);
        sSN[tid] = grid_norm[(size_t)tid * 256];
    }
    __syncthreads();

    const int lane = tid & 63, wid = tid >> 6;
    const int A = blockIdx.x >> 4, B = blockIdx.x & 15;
    const int row = A * 64 + (wid >> 1) * 32 + B * 2 + (wid & 1);

    // ---- per-row setup ----
    const float* xr = X + (size_t)row * 8;
    float  xf[8]; double xd[8], Sx = 0.0;
    uint32_t sp1b = 0, sp0sh = 0, sp1sh = 0, pp0 = 0, pp1 = 0;
#pragma unroll
    for (int j = 0; j < 8; ++j) {
        float f = xr[j]; double d = (double)f;
        xf[j] = f; xd[j] = d; Sx += d;
        uint32_t b0 = (f < 0.0f) ? 1u : 0u;
        uint32_t b1 = (d < -0.25) ? 1u : 0u;
        sp1b |= b1 << j;
        sp0sh |= b0 << shuf[j]; sp1sh |= b1 << shuf[j];
        pp0 ^= b0; pp1 ^= b1;
    }
    const float c1row = 0.5f * (float)Sx + 0.5f;   // p1 approx constant

    // ---------- approx phase (f32, candidate-A-only bounds) ----------
    float apx[8];
#pragma unroll
    for (int k = 0; k < 4; ++k) {
        const int absi = lane + (k << 6);
        float2 w01 = sWp[0][absi], w23 = sWp[1][absi], w45 = sWp[2][absi], w67 = sWp[3][absi];
        float awf[8] = {w01.x, w01.y, w23.x, w23.y, w45.x, w45.y, w67.x, w67.y};
        const float sN = sSN[absi];
        const uint32_t wpar = (sMeta[absi] >> 8) & 1u;
        float t0s[8], t1s[8];
#pragma unroll
        for (int j = 0; j < 8; ++j) { t0s[j] = awf[j] * xf[j]; t1s[j] = fmaf(t0s[j], 4.0f, awf[j]); }
        float S0 = ((fabsf(t0s[0]) + fabsf(t0s[1])) + (fabsf(t0s[2]) + fabsf(t0s[3])))
                 + ((fabsf(t0s[4]) + fabsf(t0s[5])) + (fabsf(t0s[6]) + fabsf(t0s[7])));
        float S4 = ((fabsf(t1s[0]) + fabsf(t1s[1])) + (fabsf(t1s[2]) + fabsf(t1s[3])))
                 + ((fabsf(t1s[4]) + fabsf(t1s[5])) + (fabsf(t1s[6]) + fabsf(t1s[7])));
        float m0 = t8min(t0s);
        float m4 = t8min(t1s);
        apx[2 * k]     = 2.0f * S0 - ((wpar ^ pp0) ? 4.0f * m0 : 0.0f) - sN;
        apx[2 * k + 1] = 0.5f * S4 - ((wpar ^ pp1) ? m4 : 0.0f) - sN - c1row;
    }

    float lm = apx[0];
#pragma unroll
    for (int i = 1; i < 8; ++i) lm = fmaxf(lm, apx[i]);
    const float thr = lm - EPS_SCREEN;
    uint32_t smask = 0;
#pragma unroll
    for (int i = 0; i < 8; ++i) smask |= (apx[i] >= thr ? 1u : 0u) << i;

    float bestS = -INFINITY; int bestC = 0x7fffffff;

    // ---------- exact phase (R10-identical, survivors only) ----------
    while (__any(smask != 0)) {
        if (smask) {
            const int slot = __ffs((int)smask) - 1;
            smask &= smask - 1;
            const int k = slot >> 1;
            const uint32_t p = (uint32_t)(slot & 1);
            const int absi = lane + (k << 6);

            float2 w01 = sWp[0][absi], w23 = sWp[1][absi], w45 = sWp[2][absi], w67 = sWp[3][absi];
            float awf[8] = {w01.x, w01.y, w23.x, w23.y, w45.x, w45.y, w67.x, w67.y};
            uint32_t pw0 = sPK[0][absi], pw1 = sPK[1][absi], pw2 = sPK[2][absi], pw3 = sPK[3][absi];
            uint32_t pk16[8] = {pw0 & 0xFFFFu, pw0 >> 16, pw1 & 0xFFFFu, pw1 >> 16,
                                pw2 & 0xFFFFu, pw2 >> 16, pw3 & 0xFFFFu, pw3 >> 16};
            const uint32_t meta = sMeta[absi];
            const float    sN   = sSN[absi];
            const uint32_t wsh = meta & 0xFFu, wpar = (meta >> 8) & 1u;

            double kk[8];
#pragma unroll
            for (int j = 0; j < 8; ++j) {
                double wd = (double)awf[j];
                double t0 = wd * xd[j];                       // exact
                double tt = p ? fma(t0, 4.0, wd) : t0;        // validated path
                long long ll = __double_as_longlong(tt) & 0x7FFFFFFFFFFF0000ll;
                kk[j] = __longlong_as_double(ll | (long long)pk16[j]);
            }
            double Sab = ((kk[0] + kk[1]) + (kk[2] + kk[3]))
                       + ((kk[4] + kk[5]) + (kk[6] + kk[7]));  // kk >= 0

            TournOut o = tourn8(kk);
            uint32_t sb1 = o.q1 & 0xFFu, sb2 = o.q2 & 0xFFu;
            uint32_t par = wpar ^ (p ? pp1 : pp0);
            uint32_t seffb = wsh ^ (p ? sp1sh : sp0sh);
            double dA = par ? o.a1c : 0.0;
            double dB = par ? o.a2c : (o.a1c + o.a2c);
            uint32_t sbA = par ? sb1 : 0u;
            uint32_t sbB = par ? sb2 : (sb1 ^ sb2);

            float W0 = ((((sp1b >> 0) & 1) ? -awf[0] : awf[0]) + (((sp1b >> 1) & 1) ? -awf[1] : awf[1]))
                     + ((((sp1b >> 2) & 1) ? -awf[2] : awf[2]) + (((sp1b >> 3) & 1) ? -awf[3] : awf[3]))
                     + (((((sp1b >> 4) & 1) ? -awf[4] : awf[4]) + (((sp1b >> 5) & 1) ? -awf[5] : awf[5]))
                     +  ((((sp1b >> 6) & 1) ? -awf[6] : awf[6]) + (((sp1b >> 7) & 1) ? -awf[7] : awf[7])));
            uint32_t j1 = (o.q1 >> 10) & 7u, j2 = (o.q2 >> 10) & 7u;
            float w1f = 0.5f * (float)(o.q1 >> 13);
            float w2f = 0.5f * (float)(o.q2 >> 13);
            float sw1 = ((sp1b >> j1) & 1) ? -w1f : w1f;
            float sw2 = ((sp1b >> j2) & 1) ? -w2f : w2f;
            float swA = par ? sw1 : 0.0f;
            float swB = par ? sw2 : (sw1 + sw2);
            float WcA = W0 - 2.0f * swA;
            float WcB = W0 - 2.0f * swB;

            {   double EA = (Sab - 2.0 * dA) - (p ? ((double)WcA + Sx) : 0.0);
                float fA = (float)(p ? 0.25 * EA : EA);
                float gnvA = p ? ((sN - 0.5f * WcA) + 0.5f) : sN;
                cmp_keep(bestS, bestC, 2.0f * fA - gnvA,
                         (absi << 8) | (int)(seffb ^ sbA ^ p)); }
            {   double EB = (Sab - 2.0 * dB) - (p ? ((double)WcB + Sx) : 0.0);
                float fB = (float)(p ? 0.25 * EB : EB);
                float gnvB = p ? ((sN - 0.5f * WcB) + 0.5f) : sN;
                cmp_keep(bestS, bestC, 2.0f * fB - gnvB,
                         (absi << 8) | (int)(seffb ^ sbB ^ p)); }
        }
    }

    // ---- wave reduce (ties -> lower c) ----
#pragma unroll
    for (int off = 32; off > 0; off >>= 1) {
        float s2 = __shfl_xor(bestS, off);
        int   c2 = __shfl_xor(bestC, off);
        cmp_keep(bestS, bestC, s2, c2);
    }

    if (lane == 0) {
        const int c = bestC;
        const float4* gg = reinterpret_cast<const float4*>(grid + (size_t)c * 8);
        float4* v4 = reinterpret_cast<float4*>(out + (size_t)row * 8);
        v4[0] = gg[0]; v4[1] = gg[1];
        out[65536 + row] = (float)c;
        sC[wid] = c;
    }
    __syncthreads();

    if (tid == 0) {   // fused pack: quad (A,B); waves are (i,j) = (wid>>1, wid&1)
        const uint32_t e00 = (uint32_t)sC[0], e01 = (uint32_t)sC[1];
        const uint32_t e10 = (uint32_t)sC[2], e11 = (uint32_t)sC[3];
        const uint32_t abs32 = (e00 >> 8) | ((e10 >> 8) << 8)
                             | ((e01 >> 8) << 16) | ((e11 >> 8) << 24);
        const int f = ((A >> 3) << 7) | ((B >> 2) << 5) | ((A & 7) << 2) | (B & 3);
        out[73728 + f] = (float)(int32_t)abs32;   // int32-wrap: only abs32 survives
    }
}

extern "C" void kernel_launch(void* const* d_in, const int* in_sizes, int n_in,
                              void* d_out, int out_size, void* d_ws, size_t ws_size,
                              hipStream_t stream)
{
    const float* X    = (const float*)d_in[0];
    const float* grid = (const float*)d_in[1];
    const float* gn   = (const float*)d_in[2];
    e8p_screen2<<<2048, 256, 0, stream>>>(X, grid, gn, (float*)d_out);
}